// Round 22
// baseline (531.595 us; speedup 1.0000x reference)
//
#include <hip/hip_runtime.h>
#include <hip/hip_bf16.h>
#include <hip/hip_fp16.h>

typedef __bf16 bf16;
typedef bf16 bf16x2 __attribute__((ext_vector_type(2)));
typedef bf16 bf16x4 __attribute__((ext_vector_type(4)));
typedef bf16 bf16x8 __attribute__((ext_vector_type(8)));
typedef float f32x2 __attribute__((ext_vector_type(2)));
typedef float f32x4 __attribute__((ext_vector_type(4)));

__device__ __forceinline__ void gload_lds16(const void* g, void* l) {
  __builtin_amdgcn_global_load_lds((__attribute__((address_space(1))) void*)g,
                                   (__attribute__((address_space(3))) void*)l,
                                   16, 0, 0);
}

__device__ __forceinline__ f32x2 fma2(f32x2 a, f32x2 b, f32x2 c) {
  return __builtin_elementwise_fma(a, b, c);   // -> v_pk_fma_f32
}

__device__ __forceinline__ float silu_f(float xv) {
  return xv * __builtin_amdgcn_rcpf(1.f + __expf(-xv));
}

// unpack 2 packed bf16 (u32) -> f32x2 via shift/mask (2 VALU, exact)
__device__ __forceinline__ f32x2 ubf2(unsigned int u) {
  f32x2 r;
  r.x = __uint_as_float(u << 16);
  r.y = __uint_as_float(u & 0xFFFF0000u);
  return r;
}

// ---------------- single merged prep kernel ----------------

__global__ void prep_all(const float* __restrict__ x, bf16* __restrict__ xb,
                         const float* __restrict__ uw, const float* __restrict__ vw,
                         const float* __restrict__ ow,
                         const float* __restrict__ ub, const float* __restrict__ vb,
                         bf16* __restrict__ wuv, bf16* __restrict__ owb,
                         float* __restrict__ buv,
                         const float* __restrict__ z1, const float* __restrict__ pa1,
                         const float* __restrict__ pb1, const float* __restrict__ na1,
                         const float* __restrict__ nb1,
                         const float* __restrict__ z2, const float* __restrict__ pa2,
                         const float* __restrict__ pb2, const float* __restrict__ na2,
                         const float* __restrict__ nb2,
                         unsigned int* __restrict__ Tk1, unsigned int* __restrict__ Tk2) {
  const int blk = blockIdx.x;
  if (blk < 16384) {
    const int i = blk * 256 + threadIdx.x;
    float4 v = ((const float4*)x)[i];
    bf16x4 o = {(bf16)v.x, (bf16)v.y, (bf16)v.z, (bf16)v.w};
    ((bf16x4*)xb)[i] = o;
  } else if (blk < 17920) {
    const int t = (blk - 16384) * 256 + threadIdx.x;
    if (t < 1024) { buv[t] = ub[t]; buv[1024 + t] = vb[t]; }
    const int r = t >> 17;
    const int i = t & 131071;
    const float* src = (r == 0) ? uw : (r == 1) ? vw : ow;
    bf16* dst = (r == 2) ? owb : (wuv + (r == 1) * 524288);
    float4 v = ((const float4*)src)[i];
    bf16x4 o = {(bf16)v.x, (bf16)v.y, (bf16)v.z, (bf16)v.w};
    ((bf16x4*)dst)[i] = o;
  } else {
    // Toeplitz tables: Tk[h][lag+63][cpair], u32 = 2 bf16. 2 x 8*127*64 entries.
    const int gidx = (blk - 17920) * 256 + threadIdx.x;
    if (gidx >= 2 * 8 * 127 * 64) return;
    const int which = (gidx >= 8 * 127 * 64);
    const int idx = gidx - which * (8 * 127 * 64);
    const float* zero = which ? z2 : z1;
    const float* pa = which ? pa2 : pa1;
    const float* pb = which ? pb2 : pb1;
    const float* na = which ? na2 : na1;
    const float* nb = which ? nb2 : nb1;
    const float scale = which ? 2.0f : 1.0f;   // x2 (o1+o2 fold) into table 2
    unsigned int* Tk = which ? Tk2 : Tk1;

    const int cp = idx & 63;
    const int lagIdx = (idx >> 6) % 127;
    const int h = idx / (64 * 127);
    const int lag = lagIdx - 63;
    float t0, t1;
    if (lag == 0) {
      t0 = zero[h * 128 + 2 * cp];
      t1 = zero[h * 128 + 2 * cp + 1];
    } else {
      const int k = lag > 0 ? lag : -lag;
      const float* A  = lag > 0 ? pa : na;
      const float* Bm = lag > 0 ? pb : nb;
      float pos_f = (float)(k - 1) * (15.0f / 62.0f);
      int lo = (int)floorf(pos_f);
      int hi = min(lo + 1, 15);
      float w = pos_f - (float)lo;
      float s0 = 0.f, s1 = 0.f;
      for (int r = 0; r < 32; ++r) {
        float c = (1.f - w) * A[(h * 16 + lo) * 32 + r] + w * A[(h * 16 + hi) * 32 + r];
        s0 += c * Bm[(h * 32 + r) * 128 + 2 * cp];
        s1 += c * Bm[(h * 32 + r) * 128 + 2 * cp + 1];
      }
      float dec = powf(0.999f, (float)k);
      t0 = s0 * dec;
      t1 = s1 * dec;
    }
    bf16 b0 = (bf16)(t0 * scale), b1 = (bf16)(t1 * scale);
    unsigned short u0 = *(unsigned short*)&b0, u1 = *(unsigned short*)&b1;
    Tk[idx] = (unsigned int)u0 | ((unsigned int)u1 << 16);
  }
}

// ------- GEMM: 256x256, BK=64, 8 waves, 2-buffer, 0-conflict swizzle (converged) ----

template<int MODE>
__global__ __launch_bounds__(512, 2)
void gemm8(const bf16* __restrict__ A, const bf16* __restrict__ Bm,
           const float* __restrict__ bias,
           bf16* __restrict__ out_u, bf16* __restrict__ out_v,
           float* __restrict__ out_f, int M, int N, int K) {
  __shared__ __align__(16) char lds[131072];   // 2 x (A 32KB | B 32KB)
  const int tid  = threadIdx.x;
  const int lane = tid & 63;
  const int l15  = lane & 15;
  const int lk16 = ((lane >> 4) & 3) << 4;
  const int w    = tid >> 6;
  const int wm   = (w >> 2) << 7;
  const int wn   = (w & 3) << 6;
  const int nbn  = N >> 8;
  const int cpx  = gridDim.x >> 3;
  const int swzb = (blockIdx.x & 7) * cpx + (blockIdx.x >> 3);
  const int br   = (swzb / nbn) << 8;
  const int bc   = (swzb % nbn) << 8;
  const int wub  = __builtin_amdgcn_readfirstlane(tid & 448);
  const int nkt  = K >> 6;

  f32x4 acc[8][4] = {};

  auto stage = [&](int kt, int b) {
    const int k0 = kt << 6;                    // BK=64 -> 128B rows
    char* Al = lds + b * 65536;
    char* Bl = Al + 32768;
#pragma unroll
    for (int g = 0; g < 4; ++g) {
      const int flat = g * 512 + tid;
      const int row  = flat >> 3;
      const int cb   = ((flat & 7) << 4) ^ ((row & 7) << 4);    // pre-swizzled src col
      gload_lds16((const char*)(A  + (size_t)(br + row) * K + k0) + cb,
                  Al + (g * 512 + wub) * 16);
      gload_lds16((const char*)(Bm + (size_t)(bc + row) * K + k0) + cb,
                  Bl + (g * 512 + wub) * 16);
    }
  };

  stage(0, 0);

  for (int kt = 0; kt < nkt; ++kt) {
    const int b = kt & 1;
    asm volatile("s_waitcnt vmcnt(0)" ::: "memory");   // stage(kt): issued one tile ago
    __builtin_amdgcn_s_barrier();
    __builtin_amdgcn_sched_barrier(0);
    if (kt + 1 < nkt) stage(kt + 1, b ^ 1);            // overlaps this tile's compute

    const char* Ab = lds + b * 65536;
    const char* Bb = Ab + 32768;
#pragma unroll
    for (int ks = 0; ks < 2; ++ks) {
      bf16x8 bfr[4];
#pragma unroll
      for (int n = 0; n < 4; ++n) {
        const int row = wn + n * 16 + l15;
        bfr[n] = *(const bf16x8*)(Bb + row * 128 + (((ks << 6) | lk16) ^ ((row & 7) << 4)));
      }
      __builtin_amdgcn_s_setprio(1);
#pragma unroll
      for (int m = 0; m < 8; ++m) {
        const int row = wm + m * 16 + l15;
        bf16x8 af = *(const bf16x8*)(Ab + row * 128 + (((ks << 6) | lk16) ^ ((row & 7) << 4)));
#pragma unroll
        for (int n = 0; n < 4; ++n)
          acc[m][n] = __builtin_amdgcn_mfma_f32_16x16x32_bf16(af, bfr[n], acc[m][n], 0, 0, 0);
      }
      __builtin_amdgcn_s_setprio(0);
    }
  }

  const int lr4 = ((lane >> 4) & 3) << 2;
  if (MODE == 0) {
    const bool isU = (bc < 1024);
    bf16* outp = isU ? out_u : out_v;
    const int obc = bc & 1023;
#pragma unroll
    for (int m = 0; m < 8; ++m) {
#pragma unroll
      for (int n = 0; n < 4; ++n) {
        const int colg = bc + wn + n * 16 + l15;
        const int ocol = obc + wn + n * 16 + l15;
        const float bv = bias[colg];
#pragma unroll
        for (int r = 0; r < 4; ++r) {
          const int row = br + wm + m * 16 + lr4 + r;
          outp[(size_t)row * 1024 + ocol] = (bf16)silu_f(acc[m][n][r] + bv);
        }
      }
    }
  } else {
    float bv[4];
#pragma unroll
    for (int n = 0; n < 4; ++n) bv[n] = bias[bc + wn + n * 16 + l15];
#pragma unroll
    for (int m = 0; m < 8; ++m) {
#pragma unroll
      for (int r = 0; r < 4; ++r) {
        const int row = br + wm + m * 16 + lr4 + r;
#pragma unroll
        for (int n = 0; n < 4; ++n)
          out_f[(size_t)row * N + bc + wn + n * 16 + l15] = acc[m][n][r] + bv[n];
      }
    }
  }
}

// --- Toeplitz pass v5 structure, bf16 T-table + bf16 vbuf (16.9KB LDS, 5 waves/SIMD) ---
// vbuf stores RAW bf16 (v already bf16 in memory -> staging is a pure copy: no cvt,
// half the ds_write bytes). Read-side unpack = 2 exact shift ops per j-step, amortized
// over 16 pk-fma. LDS 33.3->16.9KB + launch_bounds(256,5) (VGPR cap 102 >= measured 98)
// -> up to 5 blocks/CU on this latency-bound kernel (r18's null was a no-op: both
// (256,3) and (256,4) were already at 4 blocks physically).

#define VR2 132   // bf16 row stride (128 + 4 pad; 264B rows shift banks by 2/row)

template<int FUSE>
__global__ __launch_bounds__(256, 5)
void toep_pass(const bf16* __restrict__ in, const unsigned int* __restrict__ Tk,
               const bf16* __restrict__ ufuse, bf16* __restrict__ out,
               int stride_j, int stride_row) {
  __shared__ __align__(16) bf16 vbuf[64 * VR2];
  const int tid    = threadIdx.x;
  const int lane   = tid & 63;
  const int rowIdx = blockIdx.x >> 3;
  const int head   = blockIdx.x & 7;
  const size_t base = (size_t)(rowIdx >> 6) * 4194304
                    + (size_t)(rowIdx & 63) * stride_row + head * 128;

  const int i0 = (tid >> 6) << 4;
  const unsigned int* tg = Tk + head * 127 * 64 + lane;

  // issue jb=0 T window early (latency overlaps staging+barrier)
  f32x2 t[31];
#pragma unroll
  for (int s = 0; s < 31; ++s)
    t[s] = ubf2(tg[(i0 + 48 + s) * 64]);

  // stage v row (64 j x 128 ch) raw bf16 copy (no cvt)
#pragma unroll
  for (int it = 0; it < 2; ++it) {
    int c  = it * 256 + tid;
    int j  = c >> 3;
    int cg = c & 7;
    const bf16* p = in + base + (size_t)j * stride_j + cg * 16;
    bf16x8 a0 = *(const bf16x8*)p;
    bf16x8 a1 = *(const bf16x8*)(p + 8);
    bf16* dst = &vbuf[j * VR2 + cg * 16];
    *(bf16x8*)(dst)     = a0;
    *(bf16x8*)(dst + 8) = a1;
  }
  __syncthreads();

  f32x2 acc[16] = {};
#pragma unroll
  for (int jb = 0; jb < 4; ++jb) {
    f32x2 p16[16];
    if (jb < 3) {
#pragma unroll
      for (int s = 0; s < 16; ++s)
        p16[s] = ubf2(tg[(i0 - 16 * (jb + 1) + 48 + s) * 64]);
    }
#pragma unroll
    for (int jj = 0; jj < 16; ++jj) {
      unsigned int vu = *(const unsigned int*)&vbuf[(jb * 16 + jj) * VR2 + (lane << 1)];
      f32x2 v2 = ubf2(vu);
#pragma unroll
      for (int ii = 0; ii < 16; ++ii)
        acc[ii] = fma2(t[ii - jj + 15], v2, acc[ii]);
    }
    if (jb < 3) {
#pragma unroll
      for (int s = 30; s >= 16; --s) t[s] = t[s - 16];
#pragma unroll
      for (int s = 0; s < 16; ++s) t[s] = p16[s];
    }
  }

  const int d0 = lane << 1;
#pragma unroll
  for (int ii = 0; ii < 16; ++ii) {
    const size_t oidx = base + (size_t)(i0 + ii) * stride_j + d0;
    float a0 = acc[ii].x, a1 = acc[ii].y;
    if (FUSE) {
      bf16x2 uu = *(const bf16x2*)(ufuse + oidx);
      a0 *= (float)uu[0];
      a1 *= (float)uu[1];
    }
    bf16x2 o2 = {(bf16)a0, (bf16)a1};
    *(bf16x2*)(out + oidx) = o2;
  }
}

// ---------------- launch ----------------

extern "C" void kernel_launch(void* const* d_in, const int* in_sizes, int n_in,
                              void* d_out, int out_size, void* d_ws, size_t ws_size,
                              hipStream_t stream) {
  const float* x    = (const float*)d_in[0];
  const float* u_w  = (const float*)d_in[1];
  const float* u_b  = (const float*)d_in[2];
  const float* v_w  = (const float*)d_in[3];
  const float* v_b  = (const float*)d_in[4];
  const float* o_w  = (const float*)d_in[5];
  const float* o_b  = (const float*)d_in[6];
  const float* t1z  = (const float*)d_in[7];
  const float* t1pa = (const float*)d_in[8];
  const float* t1pb = (const float*)d_in[9];
  const float* t1na = (const float*)d_in[10];
  const float* t1nb = (const float*)d_in[11];
  const float* t2z  = (const float*)d_in[12];
  const float* t2pa = (const float*)d_in[13];
  const float* t2pb = (const float*)d_in[14];
  const float* t2na = (const float*)d_in[15];
  const float* t2nb = (const float*)d_in[16];

  char* ws = (char*)d_ws;
  size_t off = 0;
  auto alloc = [&](size_t bytes) {
    char* p = ws + off;
    off += (bytes + 255) & ~(size_t)255;
    return p;
  };
  bf16*  xb   = (bf16*)alloc(32768ull * 512 * 2);
  bf16*  wuv  = (bf16*)alloc(2048ull * 512 * 2);
  bf16*  owb  = (bf16*)alloc(512ull * 1024 * 2);
  float* buv  = (float*)alloc(2048ull * 4);
  unsigned int* Tk1 = (unsigned int*)alloc(8ull * 127 * 64 * 4);
  unsigned int* Tk2 = (unsigned int*)alloc(8ull * 127 * 64 * 4);
  bf16*  u    = (bf16*)alloc(32768ull * 1024 * 2);
  bf16*  v    = (bf16*)alloc(32768ull * 1024 * 2);
  bf16*  tmid = (bf16*)alloc(32768ull * 1024 * 2);
  bf16*  g    = v;   // v dead after toep1; reuse for gate output

  // all prep in one launch
  prep_all<<<18428, 256, 0, stream>>>(x, xb, u_w, v_w, o_w, u_b, v_b, wuv, owb, buv,
                                      t1z, t1pa, t1pb, t1na, t1nb,
                                      t2z, t2pa, t2pb, t2na, t2nb, Tk1, Tk2);

  // u,v = silu(x @ [Wu;Wv]^T + b)
  gemm8<0><<<1024, 512, 0, stream>>>(xb, wuv, buv, u, v, nullptr, 32768, 2048, 512);
  // W-axis mix (t1)
  toep_pass<0><<<4096, 256, 0, stream>>>(v, Tk1, nullptr, tmid, 1024, 65536);
  // H-axis mix (t2), gate fused (x2 in Tk2)
  toep_pass<1><<<4096, 256, 0, stream>>>(tmid, Tk2, u, g, 65536, 1024);
  // out = g @ o_w^T + o_b
  gemm8<1><<<256, 512, 0, stream>>>(g, owb, o_b, nullptr, nullptr, (float*)d_out,
                                    32768, 512, 1024);
}

// Round 23
// 271.055 us; speedup vs baseline: 1.9612x; 1.9612x over previous
//
#include <hip/hip_runtime.h>
#include <hip/hip_bf16.h>
#include <hip/hip_fp16.h>

typedef __bf16 bf16;
typedef bf16 bf16x2 __attribute__((ext_vector_type(2)));
typedef bf16 bf16x4 __attribute__((ext_vector_type(4)));
typedef bf16 bf16x8 __attribute__((ext_vector_type(8)));
typedef float f32x2 __attribute__((ext_vector_type(2)));
typedef float f32x4 __attribute__((ext_vector_type(4)));

__device__ __forceinline__ void gload_lds16(const void* g, void* l) {
  __builtin_amdgcn_global_load_lds((__attribute__((address_space(1))) void*)g,
                                   (__attribute__((address_space(3))) void*)l,
                                   16, 0, 0);
}

__device__ __forceinline__ f32x2 fma2(f32x2 a, f32x2 b, f32x2 c) {
  return __builtin_elementwise_fma(a, b, c);   // -> v_pk_fma_f32
}

__device__ __forceinline__ float silu_f(float xv) {
  return xv * __builtin_amdgcn_rcpf(1.f + __expf(-xv));
}

// unpack 2 packed bf16 (u32) -> f32x2 via shift/mask (2 VALU, exact)
__device__ __forceinline__ f32x2 ubf2(unsigned int u) {
  f32x2 r;
  r.x = __uint_as_float(u << 16);
  r.y = __uint_as_float(u & 0xFFFF0000u);
  return r;
}

// ---------------- single merged prep kernel ----------------

__global__ void prep_all(const float* __restrict__ x, bf16* __restrict__ xb,
                         const float* __restrict__ uw, const float* __restrict__ vw,
                         const float* __restrict__ ow,
                         const float* __restrict__ ub, const float* __restrict__ vb,
                         bf16* __restrict__ wuv, bf16* __restrict__ owb,
                         float* __restrict__ buv,
                         const float* __restrict__ z1, const float* __restrict__ pa1,
                         const float* __restrict__ pb1, const float* __restrict__ na1,
                         const float* __restrict__ nb1,
                         const float* __restrict__ z2, const float* __restrict__ pa2,
                         const float* __restrict__ pb2, const float* __restrict__ na2,
                         const float* __restrict__ nb2,
                         unsigned int* __restrict__ Tk1, unsigned int* __restrict__ Tk2) {
  const int blk = blockIdx.x;
  if (blk < 16384) {
    const int i = blk * 256 + threadIdx.x;
    float4 v = ((const float4*)x)[i];
    bf16x4 o = {(bf16)v.x, (bf16)v.y, (bf16)v.z, (bf16)v.w};
    ((bf16x4*)xb)[i] = o;
  } else if (blk < 17920) {
    const int t = (blk - 16384) * 256 + threadIdx.x;
    if (t < 1024) { buv[t] = ub[t]; buv[1024 + t] = vb[t]; }
    const int r = t >> 17;
    const int i = t & 131071;
    const float* src = (r == 0) ? uw : (r == 1) ? vw : ow;
    bf16* dst = (r == 2) ? owb : (wuv + (r == 1) * 524288);
    float4 v = ((const float4*)src)[i];
    bf16x4 o = {(bf16)v.x, (bf16)v.y, (bf16)v.z, (bf16)v.w};
    ((bf16x4*)dst)[i] = o;
  } else {
    // Toeplitz tables: Tk[h][lag+63][cpair], u32 = 2 bf16. 2 x 8*127*64 entries.
    const int gidx = (blk - 17920) * 256 + threadIdx.x;
    if (gidx >= 2 * 8 * 127 * 64) return;
    const int which = (gidx >= 8 * 127 * 64);
    const int idx = gidx - which * (8 * 127 * 64);
    const float* zero = which ? z2 : z1;
    const float* pa = which ? pa2 : pa1;
    const float* pb = which ? pb2 : pb1;
    const float* na = which ? na2 : na1;
    const float* nb = which ? nb2 : nb1;
    const float scale = which ? 2.0f : 1.0f;   // x2 (o1+o2 fold) into table 2
    unsigned int* Tk = which ? Tk2 : Tk1;

    const int cp = idx & 63;
    const int lagIdx = (idx >> 6) % 127;
    const int h = idx / (64 * 127);
    const int lag = lagIdx - 63;
    float t0, t1;
    if (lag == 0) {
      t0 = zero[h * 128 + 2 * cp];
      t1 = zero[h * 128 + 2 * cp + 1];
    } else {
      const int k = lag > 0 ? lag : -lag;
      const float* A  = lag > 0 ? pa : na;
      const float* Bm = lag > 0 ? pb : nb;
      float pos_f = (float)(k - 1) * (15.0f / 62.0f);
      int lo = (int)floorf(pos_f);
      int hi = min(lo + 1, 15);
      float w = pos_f - (float)lo;
      float s0 = 0.f, s1 = 0.f;
      for (int r = 0; r < 32; ++r) {
        float c = (1.f - w) * A[(h * 16 + lo) * 32 + r] + w * A[(h * 16 + hi) * 32 + r];
        s0 += c * Bm[(h * 32 + r) * 128 + 2 * cp];
        s1 += c * Bm[(h * 32 + r) * 128 + 2 * cp + 1];
      }
      float dec = powf(0.999f, (float)k);
      t0 = s0 * dec;
      t1 = s1 * dec;
    }
    bf16 b0 = (bf16)(t0 * scale), b1 = (bf16)(t1 * scale);
    unsigned short u0 = *(unsigned short*)&b0, u1 = *(unsigned short*)&b1;
    Tk[idx] = (unsigned int)u0 | ((unsigned int)u1 << 16);
  }
}

// ------- GEMM: 256x256, BK=64, 8 waves, 2-buffer, 0-conflict swizzle (converged) ----

template<int MODE>
__global__ __launch_bounds__(512, 2)
void gemm8(const bf16* __restrict__ A, const bf16* __restrict__ Bm,
           const float* __restrict__ bias,
           bf16* __restrict__ out_u, bf16* __restrict__ out_v,
           float* __restrict__ out_f, int M, int N, int K) {
  __shared__ __align__(16) char lds[131072];   // 2 x (A 32KB | B 32KB)
  const int tid  = threadIdx.x;
  const int lane = tid & 63;
  const int l15  = lane & 15;
  const int lk16 = ((lane >> 4) & 3) << 4;
  const int w    = tid >> 6;
  const int wm   = (w >> 2) << 7;
  const int wn   = (w & 3) << 6;
  const int nbn  = N >> 8;
  const int cpx  = gridDim.x >> 3;
  const int swzb = (blockIdx.x & 7) * cpx + (blockIdx.x >> 3);
  const int br   = (swzb / nbn) << 8;
  const int bc   = (swzb % nbn) << 8;
  const int wub  = __builtin_amdgcn_readfirstlane(tid & 448);
  const int nkt  = K >> 6;

  f32x4 acc[8][4] = {};

  auto stage = [&](int kt, int b) {
    const int k0 = kt << 6;                    // BK=64 -> 128B rows
    char* Al = lds + b * 65536;
    char* Bl = Al + 32768;
#pragma unroll
    for (int g = 0; g < 4; ++g) {
      const int flat = g * 512 + tid;
      const int row  = flat >> 3;
      const int cb   = ((flat & 7) << 4) ^ ((row & 7) << 4);    // pre-swizzled src col
      gload_lds16((const char*)(A  + (size_t)(br + row) * K + k0) + cb,
                  Al + (g * 512 + wub) * 16);
      gload_lds16((const char*)(Bm + (size_t)(bc + row) * K + k0) + cb,
                  Bl + (g * 512 + wub) * 16);
    }
  };

  stage(0, 0);

  for (int kt = 0; kt < nkt; ++kt) {
    const int b = kt & 1;
    asm volatile("s_waitcnt vmcnt(0)" ::: "memory");   // stage(kt): issued one tile ago
    __builtin_amdgcn_s_barrier();
    __builtin_amdgcn_sched_barrier(0);
    if (kt + 1 < nkt) stage(kt + 1, b ^ 1);            // overlaps this tile's compute

    const char* Ab = lds + b * 65536;
    const char* Bb = Ab + 32768;
#pragma unroll
    for (int ks = 0; ks < 2; ++ks) {
      bf16x8 bfr[4];
#pragma unroll
      for (int n = 0; n < 4; ++n) {
        const int row = wn + n * 16 + l15;
        bfr[n] = *(const bf16x8*)(Bb + row * 128 + (((ks << 6) | lk16) ^ ((row & 7) << 4)));
      }
      __builtin_amdgcn_s_setprio(1);
#pragma unroll
      for (int m = 0; m < 8; ++m) {
        const int row = wm + m * 16 + l15;
        bf16x8 af = *(const bf16x8*)(Ab + row * 128 + (((ks << 6) | lk16) ^ ((row & 7) << 4)));
#pragma unroll
        for (int n = 0; n < 4; ++n)
          acc[m][n] = __builtin_amdgcn_mfma_f32_16x16x32_bf16(af, bfr[n], acc[m][n], 0, 0, 0);
      }
      __builtin_amdgcn_s_setprio(0);
    }
  }

  const int lr4 = ((lane >> 4) & 3) << 2;
  if (MODE == 0) {
    const bool isU = (bc < 1024);
    bf16* outp = isU ? out_u : out_v;
    const int obc = bc & 1023;
#pragma unroll
    for (int m = 0; m < 8; ++m) {
#pragma unroll
      for (int n = 0; n < 4; ++n) {
        const int colg = bc + wn + n * 16 + l15;
        const int ocol = obc + wn + n * 16 + l15;
        const float bv = bias[colg];
#pragma unroll
        for (int r = 0; r < 4; ++r) {
          const int row = br + wm + m * 16 + lr4 + r;
          outp[(size_t)row * 1024 + ocol] = (bf16)silu_f(acc[m][n][r] + bv);
        }
      }
    }
  } else {
    float bv[4];
#pragma unroll
    for (int n = 0; n < 4; ++n) bv[n] = bias[bc + wn + n * 16 + l15];
#pragma unroll
    for (int m = 0; m < 8; ++m) {
#pragma unroll
      for (int r = 0; r < 4; ++r) {
        const int row = br + wm + m * 16 + lr4 + r;
#pragma unroll
        for (int n = 0; n < 4; ++n)
          out_f[(size_t)row * N + bc + wn + n * 16 + l15] = acc[m][n][r] + bv[n];
      }
    }
  }
}

// --- Toeplitz pass v5 structure, bf16-packed T-table, f32 vbuf, (256,3) [round-21 best] ---
// (256,5)+bf16-vbuf spilled the register window (r22: VGPR 48, scratch 500MB); (256,4)
// was physically identical to (256,3) (r18 null). This config is the measured optimum.

#define VROW 130   // f32 row stride (128 + 2 pad)

template<int FUSE>
__global__ __launch_bounds__(256, 3)
void toep_pass(const bf16* __restrict__ in, const unsigned int* __restrict__ Tk,
               const bf16* __restrict__ ufuse, bf16* __restrict__ out,
               int stride_j, int stride_row) {
  __shared__ float vbuf[64 * VROW];
  const int tid    = threadIdx.x;
  const int lane   = tid & 63;
  const int rowIdx = blockIdx.x >> 3;
  const int head   = blockIdx.x & 7;
  const size_t base = (size_t)(rowIdx >> 6) * 4194304
                    + (size_t)(rowIdx & 63) * stride_row + head * 128;

  const int i0 = (tid >> 6) << 4;
  const unsigned int* tg = Tk + head * 127 * 64 + lane;

  // issue jb=0 T window early (latency overlaps staging+barrier)
  f32x2 t[31];
#pragma unroll
  for (int s = 0; s < 31; ++s)
    t[s] = ubf2(tg[(i0 + 48 + s) * 64]);

  // stage v row (64 j x 128 ch) bf16 -> f32
#pragma unroll
  for (int it = 0; it < 2; ++it) {
    int c  = it * 256 + tid;
    int j  = c >> 3;
    int cg = c & 7;
    const bf16* p = in + base + (size_t)j * stride_j + cg * 16;
    bf16x8 a0 = *(const bf16x8*)p;
    bf16x8 a1 = *(const bf16x8*)(p + 8);
    f32x4 f0 = {(float)a0[0], (float)a0[1], (float)a0[2], (float)a0[3]};
    f32x4 f1 = {(float)a0[4], (float)a0[5], (float)a0[6], (float)a0[7]};
    f32x4 f2 = {(float)a1[0], (float)a1[1], (float)a1[2], (float)a1[3]};
    f32x4 f3 = {(float)a1[4], (float)a1[5], (float)a1[6], (float)a1[7]};
    float* dst = &vbuf[j * VROW + cg * 16];
    *(f32x4*)(dst)      = f0;
    *(f32x4*)(dst + 4)  = f1;
    *(f32x4*)(dst + 8)  = f2;
    *(f32x4*)(dst + 12) = f3;
  }
  __syncthreads();

  f32x2 acc[16] = {};
#pragma unroll
  for (int jb = 0; jb < 4; ++jb) {
    f32x2 p16[16];
    if (jb < 3) {
#pragma unroll
      for (int s = 0; s < 16; ++s)
        p16[s] = ubf2(tg[(i0 - 16 * (jb + 1) + 48 + s) * 64]);
    }
#pragma unroll
    for (int jj = 0; jj < 16; ++jj) {
      f32x2 v2 = *(const f32x2*)&vbuf[(jb * 16 + jj) * VROW + (lane << 1)];
#pragma unroll
      for (int ii = 0; ii < 16; ++ii)
        acc[ii] = fma2(t[ii - jj + 15], v2, acc[ii]);
    }
    if (jb < 3) {
#pragma unroll
      for (int s = 30; s >= 16; --s) t[s] = t[s - 16];
#pragma unroll
      for (int s = 0; s < 16; ++s) t[s] = p16[s];
    }
  }

  const int d0 = lane << 1;
#pragma unroll
  for (int ii = 0; ii < 16; ++ii) {
    const size_t oidx = base + (size_t)(i0 + ii) * stride_j + d0;
    float a0 = acc[ii].x, a1 = acc[ii].y;
    if (FUSE) {
      bf16x2 uu = *(const bf16x2*)(ufuse + oidx);
      a0 *= (float)uu[0];
      a1 *= (float)uu[1];
    }
    bf16x2 o2 = {(bf16)a0, (bf16)a1};
    *(bf16x2*)(out + oidx) = o2;
  }
}

// ---------------- launch ----------------

extern "C" void kernel_launch(void* const* d_in, const int* in_sizes, int n_in,
                              void* d_out, int out_size, void* d_ws, size_t ws_size,
                              hipStream_t stream) {
  const float* x    = (const float*)d_in[0];
  const float* u_w  = (const float*)d_in[1];
  const float* u_b  = (const float*)d_in[2];
  const float* v_w  = (const float*)d_in[3];
  const float* v_b  = (const float*)d_in[4];
  const float* o_w  = (const float*)d_in[5];
  const float* o_b  = (const float*)d_in[6];
  const float* t1z  = (const float*)d_in[7];
  const float* t1pa = (const float*)d_in[8];
  const float* t1pb = (const float*)d_in[9];
  const float* t1na = (const float*)d_in[10];
  const float* t1nb = (const float*)d_in[11];
  const float* t2z  = (const float*)d_in[12];
  const float* t2pa = (const float*)d_in[13];
  const float* t2pb = (const float*)d_in[14];
  const float* t2na = (const float*)d_in[15];
  const float* t2nb = (const float*)d_in[16];

  char* ws = (char*)d_ws;
  size_t off = 0;
  auto alloc = [&](size_t bytes) {
    char* p = ws + off;
    off += (bytes + 255) & ~(size_t)255;
    return p;
  };
  bf16*  xb   = (bf16*)alloc(32768ull * 512 * 2);
  bf16*  wuv  = (bf16*)alloc(2048ull * 512 * 2);
  bf16*  owb  = (bf16*)alloc(512ull * 1024 * 2);
  float* buv  = (float*)alloc(2048ull * 4);
  unsigned int* Tk1 = (unsigned int*)alloc(8ull * 127 * 64 * 4);
  unsigned int* Tk2 = (unsigned int*)alloc(8ull * 127 * 64 * 4);
  bf16*  u    = (bf16*)alloc(32768ull * 1024 * 2);
  bf16*  v    = (bf16*)alloc(32768ull * 1024 * 2);
  bf16*  tmid = (bf16*)alloc(32768ull * 1024 * 2);
  bf16*  g    = v;   // v dead after toep1; reuse for gate output

  // all prep in one launch: x cast + weight casts + bias + both (bf16-packed) T tables
  prep_all<<<18428, 256, 0, stream>>>(x, xb, u_w, v_w, o_w, u_b, v_b, wuv, owb, buv,
                                      t1z, t1pa, t1pb, t1na, t1nb,
                                      t2z, t2pa, t2pb, t2na, t2nb, Tk1, Tk2);

  // u,v = silu(x @ [Wu;Wv]^T + b)
  gemm8<0><<<1024, 512, 0, stream>>>(xb, wuv, buv, u, v, nullptr, 32768, 2048, 512);
  // W-axis mix (t1)
  toep_pass<0><<<4096, 256, 0, stream>>>(v, Tk1, nullptr, tmid, 1024, 65536);
  // H-axis mix (t2), gate fused (x2 in Tk2)
  toep_pass<1><<<4096, 256, 0, stream>>>(tmid, Tk2, u, g, 65536, 1024);
  // out = g @ o_w^T + o_b
  gemm8<1><<<256, 512, 0, stream>>>(g, owb, o_b, nullptr, nullptr, (float*)d_out,
                                    32768, 512, 1024);
}

// Round 24
// 270.914 us; speedup vs baseline: 1.9622x; 1.0005x over previous
//
#include <hip/hip_runtime.h>
#include <hip/hip_bf16.h>
#include <hip/hip_fp16.h>

typedef __bf16 bf16;
typedef bf16 bf16x2 __attribute__((ext_vector_type(2)));
typedef bf16 bf16x4 __attribute__((ext_vector_type(4)));
typedef bf16 bf16x8 __attribute__((ext_vector_type(8)));
typedef float f32x2 __attribute__((ext_vector_type(2)));
typedef float f32x4 __attribute__((ext_vector_type(4)));

__device__ __forceinline__ void gload_lds16(const void* g, void* l) {
  __builtin_amdgcn_global_load_lds((__attribute__((address_space(1))) void*)g,
                                   (__attribute__((address_space(3))) void*)l,
                                   16, 0, 0);
}

__device__ __forceinline__ f32x2 fma2(f32x2 a, f32x2 b, f32x2 c) {
  return __builtin_elementwise_fma(a, b, c);   // -> v_pk_fma_f32
}

__device__ __forceinline__ float silu_f(float xv) {
  return xv * __builtin_amdgcn_rcpf(1.f + __expf(-xv));
}

// unpack 2 packed bf16 (u32) -> f32x2 via shift/mask (2 VALU, exact)
__device__ __forceinline__ f32x2 ubf2(unsigned int u) {
  f32x2 r;
  r.x = __uint_as_float(u << 16);
  r.y = __uint_as_float(u & 0xFFFF0000u);
  return r;
}

// ---------------- single merged prep kernel ----------------

__global__ void prep_all(const float* __restrict__ x, bf16* __restrict__ xb,
                         const float* __restrict__ uw, const float* __restrict__ vw,
                         const float* __restrict__ ow,
                         const float* __restrict__ ub, const float* __restrict__ vb,
                         bf16* __restrict__ wuv, bf16* __restrict__ owb,
                         float* __restrict__ buv,
                         const float* __restrict__ z1, const float* __restrict__ pa1,
                         const float* __restrict__ pb1, const float* __restrict__ na1,
                         const float* __restrict__ nb1,
                         const float* __restrict__ z2, const float* __restrict__ pa2,
                         const float* __restrict__ pb2, const float* __restrict__ na2,
                         const float* __restrict__ nb2,
                         unsigned int* __restrict__ Tk1, unsigned int* __restrict__ Tk2) {
  const int blk = blockIdx.x;
  if (blk < 16384) {
    const int i = blk * 256 + threadIdx.x;
    float4 v = ((const float4*)x)[i];
    bf16x4 o = {(bf16)v.x, (bf16)v.y, (bf16)v.z, (bf16)v.w};
    ((bf16x4*)xb)[i] = o;
  } else if (blk < 17920) {
    const int t = (blk - 16384) * 256 + threadIdx.x;
    if (t < 1024) { buv[t] = ub[t]; buv[1024 + t] = vb[t]; }
    const int r = t >> 17;
    const int i = t & 131071;
    const float* src = (r == 0) ? uw : (r == 1) ? vw : ow;
    bf16* dst = (r == 2) ? owb : (wuv + (r == 1) * 524288);
    float4 v = ((const float4*)src)[i];
    bf16x4 o = {(bf16)v.x, (bf16)v.y, (bf16)v.z, (bf16)v.w};
    ((bf16x4*)dst)[i] = o;
  } else {
    // Toeplitz tables: Tk[h][lag+63][cpair], u32 = 2 bf16. 2 x 8*127*64 entries.
    const int gidx = (blk - 17920) * 256 + threadIdx.x;
    if (gidx >= 2 * 8 * 127 * 64) return;
    const int which = (gidx >= 8 * 127 * 64);
    const int idx = gidx - which * (8 * 127 * 64);
    const float* zero = which ? z2 : z1;
    const float* pa = which ? pa2 : pa1;
    const float* pb = which ? pb2 : pb1;
    const float* na = which ? na2 : na1;
    const float* nb = which ? nb2 : nb1;
    const float scale = which ? 2.0f : 1.0f;   // x2 (o1+o2 fold) into table 2
    unsigned int* Tk = which ? Tk2 : Tk1;

    const int cp = idx & 63;
    const int lagIdx = (idx >> 6) % 127;
    const int h = idx / (64 * 127);
    const int lag = lagIdx - 63;
    float t0, t1;
    if (lag == 0) {
      t0 = zero[h * 128 + 2 * cp];
      t1 = zero[h * 128 + 2 * cp + 1];
    } else {
      const int k = lag > 0 ? lag : -lag;
      const float* A  = lag > 0 ? pa : na;
      const float* Bm = lag > 0 ? pb : nb;
      float pos_f = (float)(k - 1) * (15.0f / 62.0f);
      int lo = (int)floorf(pos_f);
      int hi = min(lo + 1, 15);
      float w = pos_f - (float)lo;
      float s0 = 0.f, s1 = 0.f;
      for (int r = 0; r < 32; ++r) {
        float c = (1.f - w) * A[(h * 16 + lo) * 32 + r] + w * A[(h * 16 + hi) * 32 + r];
        s0 += c * Bm[(h * 32 + r) * 128 + 2 * cp];
        s1 += c * Bm[(h * 32 + r) * 128 + 2 * cp + 1];
      }
      float dec = powf(0.999f, (float)k);
      t0 = s0 * dec;
      t1 = s1 * dec;
    }
    bf16 b0 = (bf16)(t0 * scale), b1 = (bf16)(t1 * scale);
    unsigned short u0 = *(unsigned short*)&b0, u1 = *(unsigned short*)&b1;
    Tk[idx] = (unsigned int)u0 | ((unsigned int)u1 << 16);
  }
}

// ------- GEMM: 256x256, BK=64, 8 waves, 2-buffer, 0-conflict swizzle (converged) ----
// MODE 0 epilogue now n-inner (4 stores/row covering a contiguous 128B span -> WC
// bursts), matching the MODE 1 order validated in round 10. Pure reorder, no new ops.

template<int MODE>
__global__ __launch_bounds__(512, 2)
void gemm8(const bf16* __restrict__ A, const bf16* __restrict__ Bm,
           const float* __restrict__ bias,
           bf16* __restrict__ out_u, bf16* __restrict__ out_v,
           float* __restrict__ out_f, int M, int N, int K) {
  __shared__ __align__(16) char lds[131072];   // 2 x (A 32KB | B 32KB)
  const int tid  = threadIdx.x;
  const int lane = tid & 63;
  const int l15  = lane & 15;
  const int lk16 = ((lane >> 4) & 3) << 4;
  const int w    = tid >> 6;
  const int wm   = (w >> 2) << 7;
  const int wn   = (w & 3) << 6;
  const int nbn  = N >> 8;
  const int cpx  = gridDim.x >> 3;
  const int swzb = (blockIdx.x & 7) * cpx + (blockIdx.x >> 3);
  const int br   = (swzb / nbn) << 8;
  const int bc   = (swzb % nbn) << 8;
  const int wub  = __builtin_amdgcn_readfirstlane(tid & 448);
  const int nkt  = K >> 6;

  f32x4 acc[8][4] = {};

  auto stage = [&](int kt, int b) {
    const int k0 = kt << 6;                    // BK=64 -> 128B rows
    char* Al = lds + b * 65536;
    char* Bl = Al + 32768;
#pragma unroll
    for (int g = 0; g < 4; ++g) {
      const int flat = g * 512 + tid;
      const int row  = flat >> 3;
      const int cb   = ((flat & 7) << 4) ^ ((row & 7) << 4);    // pre-swizzled src col
      gload_lds16((const char*)(A  + (size_t)(br + row) * K + k0) + cb,
                  Al + (g * 512 + wub) * 16);
      gload_lds16((const char*)(Bm + (size_t)(bc + row) * K + k0) + cb,
                  Bl + (g * 512 + wub) * 16);
    }
  };

  stage(0, 0);

  for (int kt = 0; kt < nkt; ++kt) {
    const int b = kt & 1;
    asm volatile("s_waitcnt vmcnt(0)" ::: "memory");   // stage(kt): issued one tile ago
    __builtin_amdgcn_s_barrier();
    __builtin_amdgcn_sched_barrier(0);
    if (kt + 1 < nkt) stage(kt + 1, b ^ 1);            // overlaps this tile's compute

    const char* Ab = lds + b * 65536;
    const char* Bb = Ab + 32768;
#pragma unroll
    for (int ks = 0; ks < 2; ++ks) {
      bf16x8 bfr[4];
#pragma unroll
      for (int n = 0; n < 4; ++n) {
        const int row = wn + n * 16 + l15;
        bfr[n] = *(const bf16x8*)(Bb + row * 128 + (((ks << 6) | lk16) ^ ((row & 7) << 4)));
      }
      __builtin_amdgcn_s_setprio(1);
#pragma unroll
      for (int m = 0; m < 8; ++m) {
        const int row = wm + m * 16 + l15;
        bf16x8 af = *(const bf16x8*)(Ab + row * 128 + (((ks << 6) | lk16) ^ ((row & 7) << 4)));
#pragma unroll
        for (int n = 0; n < 4; ++n)
          acc[m][n] = __builtin_amdgcn_mfma_f32_16x16x32_bf16(af, bfr[n], acc[m][n], 0, 0, 0);
      }
      __builtin_amdgcn_s_setprio(0);
    }
  }

  const int lr4 = ((lane >> 4) & 3) << 2;
  if (MODE == 0) {
    const bool isU = (bc < 1024);
    bf16* outp = isU ? out_u : out_v;
    const int obc = bc & 1023;
    float bv[4];
#pragma unroll
    for (int n = 0; n < 4; ++n) bv[n] = bias[bc + wn + n * 16 + l15];
#pragma unroll
    for (int m = 0; m < 8; ++m) {
#pragma unroll
      for (int r = 0; r < 4; ++r) {
        const int row = br + wm + m * 16 + lr4 + r;
#pragma unroll
        for (int n = 0; n < 4; ++n) {
          const int ocol = obc + wn + n * 16 + l15;
          outp[(size_t)row * 1024 + ocol] = (bf16)silu_f(acc[m][n][r] + bv[n]);
        }
      }
    }
  } else {
    float bv[4];
#pragma unroll
    for (int n = 0; n < 4; ++n) bv[n] = bias[bc + wn + n * 16 + l15];
#pragma unroll
    for (int m = 0; m < 8; ++m) {
#pragma unroll
      for (int r = 0; r < 4; ++r) {
        const int row = br + wm + m * 16 + lr4 + r;
#pragma unroll
        for (int n = 0; n < 4; ++n)
          out_f[(size_t)row * N + bc + wn + n * 16 + l15] = acc[m][n][r] + bv[n];
      }
    }
  }
}

// --- Toeplitz pass v5 structure, bf16-packed T-table, f32 vbuf, (256,3) [converged] ---

#define VROW 130   // f32 row stride (128 + 2 pad)

template<int FUSE>
__global__ __launch_bounds__(256, 3)
void toep_pass(const bf16* __restrict__ in, const unsigned int* __restrict__ Tk,
               const bf16* __restrict__ ufuse, bf16* __restrict__ out,
               int stride_j, int stride_row) {
  __shared__ float vbuf[64 * VROW];
  const int tid    = threadIdx.x;
  const int lane   = tid & 63;
  const int rowIdx = blockIdx.x >> 3;
  const int head   = blockIdx.x & 7;
  const size_t base = (size_t)(rowIdx >> 6) * 4194304
                    + (size_t)(rowIdx & 63) * stride_row + head * 128;

  const int i0 = (tid >> 6) << 4;
  const unsigned int* tg = Tk + head * 127 * 64 + lane;

  // issue jb=0 T window early (latency overlaps staging+barrier)
  f32x2 t[31];
#pragma unroll
  for (int s = 0; s < 31; ++s)
    t[s] = ubf2(tg[(i0 + 48 + s) * 64]);

  // stage v row (64 j x 128 ch) bf16 -> f32
#pragma unroll
  for (int it = 0; it < 2; ++it) {
    int c  = it * 256 + tid;
    int j  = c >> 3;
    int cg = c & 7;
    const bf16* p = in + base + (size_t)j * stride_j + cg * 16;
    bf16x8 a0 = *(const bf16x8*)p;
    bf16x8 a1 = *(const bf16x8*)(p + 8);
    f32x4 f0 = {(float)a0[0], (float)a0[1], (float)a0[2], (float)a0[3]};
    f32x4 f1 = {(float)a0[4], (float)a0[5], (float)a0[6], (float)a0[7]};
    f32x4 f2 = {(float)a1[0], (float)a1[1], (float)a1[2], (float)a1[3]};
    f32x4 f3 = {(float)a1[4], (float)a1[5], (float)a1[6], (float)a1[7]};
    float* dst = &vbuf[j * VROW + cg * 16];
    *(f32x4*)(dst)      = f0;
    *(f32x4*)(dst + 4)  = f1;
    *(f32x4*)(dst + 8)  = f2;
    *(f32x4*)(dst + 12) = f3;
  }
  __syncthreads();

  f32x2 acc[16] = {};
#pragma unroll
  for (int jb = 0; jb < 4; ++jb) {
    f32x2 p16[16];
    if (jb < 3) {
#pragma unroll
      for (int s = 0; s < 16; ++s)
        p16[s] = ubf2(tg[(i0 - 16 * (jb + 1) + 48 + s) * 64]);
    }
#pragma unroll
    for (int jj = 0; jj < 16; ++jj) {
      f32x2 v2 = *(const f32x2*)&vbuf[(jb * 16 + jj) * VROW + (lane << 1)];
#pragma unroll
      for (int ii = 0; ii < 16; ++ii)
        acc[ii] = fma2(t[ii - jj + 15], v2, acc[ii]);
    }
    if (jb < 3) {
#pragma unroll
      for (int s = 30; s >= 16; --s) t[s] = t[s - 16];
#pragma unroll
      for (int s = 0; s < 16; ++s) t[s] = p16[s];
    }
  }

  const int d0 = lane << 1;
#pragma unroll
  for (int ii = 0; ii < 16; ++ii) {
    const size_t oidx = base + (size_t)(i0 + ii) * stride_j + d0;
    float a0 = acc[ii].x, a1 = acc[ii].y;
    if (FUSE) {
      bf16x2 uu = *(const bf16x2*)(ufuse + oidx);
      a0 *= (float)uu[0];
      a1 *= (float)uu[1];
    }
    bf16x2 o2 = {(bf16)a0, (bf16)a1};
    *(bf16x2*)(out + oidx) = o2;
  }
}

// ---------------- launch ----------------

extern "C" void kernel_launch(void* const* d_in, const int* in_sizes, int n_in,
                              void* d_out, int out_size, void* d_ws, size_t ws_size,
                              hipStream_t stream) {
  const float* x    = (const float*)d_in[0];
  const float* u_w  = (const float*)d_in[1];
  const float* u_b  = (const float*)d_in[2];
  const float* v_w  = (const float*)d_in[3];
  const float* v_b  = (const float*)d_in[4];
  const float* o_w  = (const float*)d_in[5];
  const float* o_b  = (const float*)d_in[6];
  const float* t1z  = (const float*)d_in[7];
  const float* t1pa = (const float*)d_in[8];
  const float* t1pb = (const float*)d_in[9];
  const float* t1na = (const float*)d_in[10];
  const float* t1nb = (const float*)d_in[11];
  const float* t2z  = (const float*)d_in[12];
  const float* t2pa = (const float*)d_in[13];
  const float* t2pb = (const float*)d_in[14];
  const float* t2na = (const float*)d_in[15];
  const float* t2nb = (const float*)d_in[16];

  char* ws = (char*)d_ws;
  size_t off = 0;
  auto alloc = [&](size_t bytes) {
    char* p = ws + off;
    off += (bytes + 255) & ~(size_t)255;
    return p;
  };
  bf16*  xb   = (bf16*)alloc(32768ull * 512 * 2);
  bf16*  wuv  = (bf16*)alloc(2048ull * 512 * 2);
  bf16*  owb  = (bf16*)alloc(512ull * 1024 * 2);
  float* buv  = (float*)alloc(2048ull * 4);
  unsigned int* Tk1 = (unsigned int*)alloc(8ull * 127 * 64 * 4);
  unsigned int* Tk2 = (unsigned int*)alloc(8ull * 127 * 64 * 4);
  bf16*  u    = (bf16*)alloc(32768ull * 1024 * 2);
  bf16*  v    = (bf16*)alloc(32768ull * 1024 * 2);
  bf16*  tmid = (bf16*)alloc(32768ull * 1024 * 2);
  bf16*  g    = v;   // v dead after toep1; reuse for gate output

  // all prep in one launch: x cast + weight casts + bias + both (bf16-packed) T tables
  prep_all<<<18428, 256, 0, stream>>>(x, xb, u_w, v_w, o_w, u_b, v_b, wuv, owb, buv,
                                      t1z, t1pa, t1pb, t1na, t1nb,
                                      t2z, t2pa, t2pb, t2na, t2nb, Tk1, Tk2);

  // u,v = silu(x @ [Wu;Wv]^T + b)
  gemm8<0><<<1024, 512, 0, stream>>>(xb, wuv, buv, u, v, nullptr, 32768, 2048, 512);
  // W-axis mix (t1)
  toep_pass<0><<<4096, 256, 0, stream>>>(v, Tk1, nullptr, tmid, 1024, 65536);
  // H-axis mix (t2), gate fused (x2 in Tk2)
  toep_pass<1><<<4096, 256, 0, stream>>>(tmid, Tk2, u, g, 65536, 1024);
  // out = g @ o_w^T + o_b
  gemm8<1><<<256, 512, 0, stream>>>(g, owb, o_b, nullptr, nullptr, (float*)d_out,
                                    32768, 512, 1024);
}